// Round 7
// baseline (177.554 us; speedup 1.0000x reference)
//
#include <hip/hip_runtime.h>

typedef unsigned short u16;
typedef __attribute__((ext_vector_type(4))) float f32x4;
typedef __attribute__((ext_vector_type(8))) __bf16 bf16x8;
typedef __attribute__((ext_vector_type(8))) u16 u16x8;
typedef __attribute__((ext_vector_type(4))) u16 u16x4;

#define S_LEN 2048
#define NH 16
#define NKV 8
// sqrt(128) * log2(e) folded into Q at rope_norm; softmax runs in exp2 space
#define QSCALE_LOG2E 16.322118857f
#define M2INIT 16.6f   /* fixed max: |s2| <= 16.33*(1+bf16 eps) < 16.5 */
#define EXP2(x) __builtin_amdgcn_exp2f(x)

#define AS1(p) ((const __attribute__((address_space(1))) void*)(p))
#define AS3(p) ((__attribute__((address_space(3))) void*)(p))

__device__ __forceinline__ float b2f(u16 u) {
    return __uint_as_float(((unsigned int)u) << 16);
}
__device__ __forceinline__ u16 f2b(float f) {
    unsigned int x = __float_as_uint(f);
    unsigned int r = (x + 0x7FFFu + ((x >> 16) & 1u)) >> 16;
    return (u16)r;
}

// ---------------------------------------------------------------- fused casts
__global__ __launch_bounds__(256) void cast_all(const float* __restrict__ hs,
                                                const float* __restrict__ Wq,
                                                const float* __restrict__ Wk,
                                                const float* __restrict__ Wv,
                                                const float* __restrict__ Wo,
                                                u16* __restrict__ hsb,
                                                u16* __restrict__ wcat,
                                                u16* __restrict__ wob) {
    int i = blockIdx.x * 256 + threadIdx.x;   // 0 .. 4194303 quads
    const float* src; u16* dst; int off;
    if (i < 1048576)      { src = hs; dst = hsb;            off = i; }
    else if (i < 2097152) { src = Wq; dst = wcat;           off = i - 1048576; }
    else if (i < 2621440) { src = Wk; dst = wcat + 4194304; off = i - 2097152; }
    else if (i < 3145728) { src = Wv; dst = wcat + 6291456; off = i - 2621440; }
    else                  { src = Wo; dst = wob;            off = i - 3145728; }
    f32x4 v = reinterpret_cast<const f32x4*>(src)[off];
    u16x4 o;
    o[0] = f2b(v[0]); o[1] = f2b(v[1]); o[2] = f2b(v[2]); o[3] = f2b(v[3]);
    reinterpret_cast<u16x4*>(dst)[off] = o;
}

// V slice of QKVf -> vt [gd=g*128+d][s] bf16 (transposed for PV B-frags)
__global__ __launch_bounds__(256) void cast_v_t(const float* __restrict__ qkvf,
                                                u16* __restrict__ vt) {
    __shared__ float tile[64][65];
    int s0 = (blockIdx.x & 31) * 64;
    int c0 = (blockIdx.x >> 5) * 64;
    for (int i = threadIdx.x; i < 64 * 64; i += 256) {
        int r = i >> 6, c = i & 63;
        tile[r][c] = qkvf[(size_t)(s0 + r) * 4096 + 3072 + c0 + c];
    }
    __syncthreads();
    for (int i = threadIdx.x; i < 64 * 64; i += 256) {
        int r = i >> 6, c = i & 63;
        vt[(size_t)(c0 + r) * 2048 + s0 + c] = f2b(tile[c][r]);
    }
}

// ---------------------------------------------------------------- GEMM (dbuf 2-phase, 8 waves)
// C[M][N] = A[M][K] * B[N][K]^T, bf16 in, f32 out. BK=64, double-buffered
// linear LDS + global_load_lds(16B); prefetch issued before compute, one
// __syncthreads per K-step. 512 threads = 8 waves (WM x WN wave grid) for
// 16 waves/CU at 2 blocks/CU (was 8 -> latency-bound at Occupancy 19%).
template<int BM, int BN, int WM, int WN>
__global__ __launch_bounds__(512) void gemm_t(const u16* __restrict__ A,
                                              const u16* __restrict__ B,
                                              float* __restrict__ C,
                                              int M, int N, int K) {
    constexpr int MR = BM / WM / 16;
    constexpr int NR = BN / WN / 16;
    __shared__ alignas(16) u16 As[2][BM * 64];
    __shared__ alignas(16) u16 Bs[2][BN * 64];
    int tid = threadIdx.x, lane = tid & 63, wave = tid >> 6;   // 8 waves
    int row0 = blockIdx.y * BM, col0 = blockIdx.x * BN;
    int wr = (wave / WN) * (BM / WM);
    int wc = (wave % WN) * (BN / WN);
    int l15 = lane & 15, lg = lane >> 4;

    f32x4 acc[MR][NR] = {};

    auto stage = [&](int bf, int k0) {
#pragma unroll
        for (int i = 0; i < BM / 64; i++) {
            int slot = i * 8 + wave;            // wave-uniform
            int r = slot * 8 + (lane >> 3);
            int c = lane & 7;
            __builtin_amdgcn_global_load_lds(AS1(A + (size_t)(row0 + r) * K + k0 + c * 8),
                                             AS3(&As[bf][slot * 512]), 16, 0, 0);
        }
#pragma unroll
        for (int i = 0; i < BN / 64; i++) {
            int slot = i * 8 + wave;
            int r = slot * 8 + (lane >> 3);
            int c = lane & 7;
            __builtin_amdgcn_global_load_lds(AS1(B + (size_t)(col0 + r) * K + k0 + c * 8),
                                             AS3(&Bs[bf][slot * 512]), 16, 0, 0);
        }
    };

    stage(0, 0);
    __syncthreads();

    int nk = K >> 6, buf = 0;
    for (int t = 0; t < nk; ++t) {
        if (t + 1 < nk) stage(buf ^ 1, (t + 1) * 64);

        __builtin_amdgcn_s_setprio(1);
#pragma unroll
        for (int kk = 0; kk < 2; kk++) {
            bf16x8 af[MR], bg[NR];
#pragma unroll
            for (int m = 0; m < MR; m++)
                af[m] = *reinterpret_cast<const bf16x8*>(&As[buf][(wr + m * 16 + l15) * 64 + kk * 32 + lg * 8]);
#pragma unroll
            for (int n = 0; n < NR; n++)
                bg[n] = *reinterpret_cast<const bf16x8*>(&Bs[buf][(wc + n * 16 + l15) * 64 + kk * 32 + lg * 8]);
#pragma unroll
            for (int m = 0; m < MR; m++)
#pragma unroll
                for (int n = 0; n < NR; n++)
                    acc[m][n] = __builtin_amdgcn_mfma_f32_16x16x32_bf16(af[m], bg[n], acc[m][n], 0, 0, 0);
        }
        __builtin_amdgcn_s_setprio(0);

        __syncthreads();
        buf ^= 1;
    }

#pragma unroll
    for (int m = 0; m < MR; m++)
#pragma unroll
        for (int n = 0; n < NR; n++)
#pragma unroll
            for (int r = 0; r < 4; r++) {
                int row = row0 + wr + m * 16 + lg * 4 + r;
                int col = col0 + wc + n * 16 + l15;
                C[(size_t)row * N + col] = acc[m][n][r];
            }
}

// ---------------------------------------------------------------- fused RoPE + L2 norm (Q and K)
__global__ __launch_bounds__(256) void rope_norm(const float* __restrict__ qkvf,
                                                 const float* __restrict__ cosb,
                                                 const float* __restrict__ sinb,
                                                 const float* __restrict__ sqkw,
                                                 u16* __restrict__ qb,
                                                 u16* __restrict__ kb) {
    int w = blockIdx.x * 4 + (threadIdx.x >> 6);
    int lane = threadIdx.x & 63;
    bool isQ = w < 32768;
    const float* src;
    int s, hg;
    if (isQ) { hg = w & (NH - 1); s = w >> 4; src = qkvf + (size_t)s * 4096 + hg * 128; }
    else     { int w2 = w - 32768; hg = w2 & (NKV - 1); s = w2 >> 3; src = qkvf + (size_t)s * 4096 + 2048 + hg * 128; }
    float x0 = src[lane], x1 = src[lane + 64];
    float c0 = cosb[s * 128 + lane], c1 = cosb[s * 128 + 64 + lane];
    float s0 = sinb[s * 128 + lane], s1 = sinb[s * 128 + 64 + lane];
    float y0 = x0 * c0 - x1 * s0;
    float y1 = x1 * c1 + x0 * s1;
    float ss = y0 * y0 + y1 * y1;
#pragma unroll
    for (int off = 32; off; off >>= 1) ss += __shfl_xor(ss, off);
    float inv = 1.f / (sqrtf(ss) + 1e-8f);
    if (isQ) {
        float w0 = sqkw[hg * 128 + lane] * 50.f;
        float w1 = sqkw[hg * 128 + 64 + lane] * 50.f;
        u16* dst = qb + ((size_t)hg * S_LEN + s) * 128;
        dst[lane]      = f2b(y0 * inv * w0 * w0 * QSCALE_LOG2E);
        dst[lane + 64] = f2b(y1 * inv * w1 * w1 * QSCALE_LOG2E);
    } else {
        u16* dst = kb + ((size_t)hg * S_LEN + s) * 128;
        dst[lane]      = f2b(y0 * inv);
        dst[lane + 64] = f2b(y1 * inv);
    }
}

// ---------------------------------------------------------------- MFMA flash attention
// 64 q-rows/block, 4 waves x 16 rows. K-tiles of 64. Single LDS buffer
// (41KB -> 3 blocks/CU), T14 async-STAGE split. Softmax in exp2 space with
// fixed max (nGPT bound |s2|<16.5), defer-max cold path as guard.
__global__ __launch_bounds__(256) void attn_mfma(const u16* __restrict__ Qb,  // [16][S][128]
                                                 const u16* __restrict__ Kb,  // [8][S][128]
                                                 const u16* __restrict__ Vt,  // [1024][S]
                                                 u16* __restrict__ Ao) {      // [S][2048]
    __shared__ alignas(16) u16 Ks[64 * 128];
    __shared__ alignas(16) u16 Vs[128 * 64];
    __shared__ alignas(16) u16 Pb[4][16][72];

    int tid = threadIdx.x, lane = tid & 63, wv = tid >> 6;
    int h = blockIdx.x & (NH - 1);
    int z = blockIdx.x >> 4;
    int qi = (z < 16) ? (31 - z) : (z - 16);   // pair big+small per CU
    int qb0 = qi * 64;
    int g = h >> 1;
    int l15 = lane & 15, lg = lane >> 4;

    // Q fragments from global (one-time, L2-resident); pre-scaled by sqrt(D)*log2e
    bf16x8 qf[4];
    {
        const u16* qrow = Qb + ((size_t)h * S_LEN + qb0 + wv * 16 + l15) * 128;
#pragma unroll
        for (int kd = 0; kd < 4; kd++)
            qf[kd] = *reinterpret_cast<const bf16x8*>(qrow + kd * 32 + lg * 8);
    }

    const u16* kbase = Kb + (size_t)g * S_LEN * 128;
    const u16* vbase = Vt + (size_t)g * 128 * S_LEN;

    // reg-staging mapping: whole-row coverage per wave-write => conflict-free
    int rk = wv * 16 + (lane >> 4);   // K row (+4*i), chunk ck (16B) of 256B row
    int ck = lane & 15;
    int rv = wv * 32 + (lane >> 3);   // V row (+8*i), chunk cv (16B) of 128B row
    int cv = lane & 7;

    u16x8 kreg[4], vreg[4];

    float m2[4], lpart[4];
    f32x4 oacc[8];
#pragma unroll
    for (int r = 0; r < 4; r++) { m2[r] = M2INIT; lpart[r] = 0.f; }
#pragma unroll
    for (int dt = 0; dt < 8; dt++) oacc[dt] = (f32x4){0.f, 0.f, 0.f, 0.f};

    int nt = qi + 1;

    // prologue: load tile 0 into regs
#pragma unroll
    for (int i = 0; i < 4; i++) {
        kreg[i] = *reinterpret_cast<const u16x8*>(kbase + (size_t)(rk + 4 * i) * 128 + ck * 8);
        vreg[i] = *reinterpret_cast<const u16x8*>(vbase + (size_t)(rv + 8 * i) * S_LEN + cv * 8);
    }

    for (int t = 0; t < nt; ++t) {
        int k0 = t * 64;
        __syncthreads();   // all waves done reading previous tile
        // write staged regs -> LDS (swizzled)
#pragma unroll
        for (int i = 0; i < 4; i++) {
            int r = rk + 4 * i;
            *reinterpret_cast<u16x8*>((char*)Ks + r * 256 + ((ck * 16) ^ ((r & 7) << 4))) = kreg[i];
            int r2 = rv + 8 * i;
            *reinterpret_cast<u16x8*>((char*)Vs + r2 * 128 + ((cv * 16) ^ ((r2 & 7) << 4))) = vreg[i];
        }
        __syncthreads();   // LDS visible

        // issue next tile's global loads now; they complete under compute
        if (t + 1 < nt) {
            int kn = k0 + 64;
#pragma unroll
            for (int i = 0; i < 4; i++) {
                kreg[i] = *reinterpret_cast<const u16x8*>(kbase + (size_t)(kn + rk + 4 * i) * 128 + ck * 8);
                vreg[i] = *reinterpret_cast<const u16x8*>(vbase + (size_t)(rv + 8 * i) * S_LEN + kn + cv * 8);
            }
        }

        // S2 = (Q*log2e*sqrt(D)) K^T
        f32x4 sacc[4];
#pragma unroll
        for (int kt = 0; kt < 4; kt++) sacc[kt] = (f32x4){0.f, 0.f, 0.f, 0.f};
        __builtin_amdgcn_s_setprio(1);
#pragma unroll
        for (int kt = 0; kt < 4; kt++) {
            int r = kt * 16 + l15;
#pragma unroll
            for (int kd = 0; kd < 4; kd++) {
                int col = kd * 64 + lg * 16;
                bf16x8 kf = *reinterpret_cast<const bf16x8*>((char*)Ks + r * 256 + (col ^ ((r & 7) << 4)));
                sacc[kt] = __builtin_amdgcn_mfma_f32_16x16x32_bf16(qf[kd], kf, sacc[kt], 0, 0, 0);
            }
        }
        __builtin_amdgcn_s_setprio(0);

        // causal mask (diagonal tile only)
        if (t == nt - 1) {
#pragma unroll
            for (int kt = 0; kt < 4; kt++)
#pragma unroll
                for (int r = 0; r < 4; r++) {
                    int key = k0 + kt * 16 + l15;
                    int q = qb0 + wv * 16 + lg * 4 + r;
                    if (key > q) sacc[kt][r] = -1e30f;
                }
        }

        // softmax, exp2 space, fixed max + defer-max guard
        int need = 0;
#pragma unroll
        for (int r = 0; r < 4; r++) {
            float tm = fmaxf(fmaxf(sacc[0][r], sacc[1][r]), fmaxf(sacc[2][r], sacc[3][r]));
            need |= (tm > m2[r] + 11.5f) ? 1 : 0;
        }
        if (__builtin_expect(__any(need), 0)) {
            // cold path: true online-softmax rescale (universal correctness)
#pragma unroll
            for (int r = 0; r < 4; r++) {
                float tm = fmaxf(fmaxf(sacc[0][r], sacc[1][r]), fmaxf(sacc[2][r], sacc[3][r]));
                tm = fmaxf(tm, __shfl_xor(tm, 1));
                tm = fmaxf(tm, __shfl_xor(tm, 2));
                tm = fmaxf(tm, __shfl_xor(tm, 4));
                tm = fmaxf(tm, __shfl_xor(tm, 8));
                float mn = fmaxf(m2[r], tm);
                float sc = EXP2(m2[r] - mn);
                m2[r] = mn;
                lpart[r] *= sc;
#pragma unroll
                for (int dt = 0; dt < 8; dt++) oacc[dt][r] *= sc;
            }
        }
        float pnew[4][4];
#pragma unroll
        for (int r = 0; r < 4; r++) {
            float p0 = EXP2(sacc[0][r] - m2[r]);
            float p1 = EXP2(sacc[1][r] - m2[r]);
            float p2 = EXP2(sacc[2][r] - m2[r]);
            float p3 = EXP2(sacc[3][r] - m2[r]);
            pnew[0][r] = p0; pnew[1][r] = p1; pnew[2][r] = p2; pnew[3][r] = p3;
            lpart[r] += (p0 + p1) + (p2 + p3);
        }

        // P -> wave-private LDS (re-layout for PV A-frags)
#pragma unroll
        for (int kt = 0; kt < 4; kt++)
#pragma unroll
            for (int r = 0; r < 4; r++)
                Pb[wv][lg * 4 + r][kt * 16 + l15] = f2b(pnew[kt][r]);

        // O += P V
        __builtin_amdgcn_s_setprio(1);
#pragma unroll
        for (int ks = 0; ks < 2; ks++) {
            bf16x8 pf = *reinterpret_cast<const bf16x8*>(&Pb[wv][l15][ks * 32 + lg * 8]);
#pragma unroll
            for (int dt = 0; dt < 8; dt++) {
                int r = dt * 16 + l15;
                int col = ks * 64 + lg * 16;
                bf16x8 vf = *reinterpret_cast<const bf16x8*>((char*)Vs + r * 128 + (col ^ ((r & 7) << 4)));
                oacc[dt] = __builtin_amdgcn_mfma_f32_16x16x32_bf16(pf, vf, oacc[dt], 0, 0, 0);
            }
        }
        __builtin_amdgcn_s_setprio(0);
    }

    // epilogue: one-time l reduce across the 16-lane row groups
    float inv[4];
#pragma unroll
    for (int r = 0; r < 4; r++) {
        float ls = lpart[r];
        ls += __shfl_xor(ls, 1);
        ls += __shfl_xor(ls, 2);
        ls += __shfl_xor(ls, 4);
        ls += __shfl_xor(ls, 8);
        inv[r] = 1.f / ls;
    }
#pragma unroll
    for (int dt = 0; dt < 8; dt++)
#pragma unroll
        for (int r = 0; r < 4; r++) {
            int q = qb0 + wv * 16 + lg * 4 + r;
            Ao[(size_t)q * 2048 + h * 128 + dt * 16 + l15] = f2b(oacc[dt][r] * inv[r]);
        }
}

// ---------------------------------------------------------------- launch
extern "C" void kernel_launch(void* const* d_in, const int* in_sizes, int n_in,
                              void* d_out, int out_size, void* d_ws, size_t ws_size,
                              hipStream_t stream) {
    const float* hs   = (const float*)d_in[0];
    const float* cosb = (const float*)d_in[1];
    const float* sinb = (const float*)d_in[2];
    // d_in[3] attention_mask: pure causal, implemented analytically
    const float* Wq   = (const float*)d_in[4];
    const float* Wk   = (const float*)d_in[5];
    const float* Wv   = (const float*)d_in[6];
    const float* Wo   = (const float*)d_in[7];
    const float* sqkw = (const float*)d_in[8];

    char* ws = (char*)d_ws;
    u16*   hsb  = (u16*)(ws);                       //  8.4 MB
    u16*   wcat = (u16*)(ws + 8388608);             // 16.8 MB (Wq;Wk;Wv)
    u16*   wob  = (u16*)(ws + 25165824);            //  8.4 MB
    float* qkvf = (float*)(ws + 33554432);          // 33.6 MB
    u16*   qb   = (u16*)(ws + 67108864);            //  8.4 MB
    u16*   kb   = (u16*)(ws + 75497472);            //  4.2 MB
    u16*   vt   = (u16*)(ws + 79691776);            //  4.2 MB (V^T)
    u16*   ao   = (u16*)(ws + 83886080);            //  8.4 MB

    cast_all<<<16384, 256, 0, stream>>>(hs, Wq, Wk, Wv, Wo, hsb, wcat, wob);

    // QKV projection: 8-wave blocks, 2M x 4N wave grid
    gemm_t<128, 128, 2, 4><<<dim3(32, 16), 512, 0, stream>>>(hsb, wcat, qkvf, 2048, 4096, 2048);

    rope_norm<<<12288, 256, 0, stream>>>(qkvf, cosb, sinb, sqkw, qb, kb);
    cast_v_t<<<512, 256, 0, stream>>>(qkvf, vt);

    attn_mfma<<<512, 256, 0, stream>>>(qb, kb, vt, ao);

    // output projection: 8-wave blocks, 4M x 2N wave grid, 128x64 tiles
    gemm_t<128, 64, 4, 2><<<dim3(32, 16), 512, 0, stream>>>(ao, wob, (float*)d_out, 2048, 2048, 2048);
}

// Round 8
// 163.861 us; speedup vs baseline: 1.0836x; 1.0836x over previous
//
#include <hip/hip_runtime.h>

typedef unsigned short u16;
typedef __attribute__((ext_vector_type(4))) float f32x4;
typedef __attribute__((ext_vector_type(8))) __bf16 bf16x8;
typedef __attribute__((ext_vector_type(8))) u16 u16x8;
typedef __attribute__((ext_vector_type(4))) u16 u16x4;

#define S_LEN 2048
#define NH 16
#define NKV 8
// sqrt(128) * log2(e) folded into Q; softmax runs in exp2 space
#define QSCALE_LOG2E 16.322118857f
#define M2INIT 16.6f   /* fixed max: |s2| <= 16.33*(1+bf16 eps) < 16.5 */
#define EXP2(x) __builtin_amdgcn_exp2f(x)

#define AS1(p) ((const __attribute__((address_space(1))) void*)(p))
#define AS3(p) ((__attribute__((address_space(3))) void*)(p))

__device__ __forceinline__ float b2f(u16 u) {
    return __uint_as_float(((unsigned int)u) << 16);
}
__device__ __forceinline__ u16 f2b(float f) {
    unsigned int x = __float_as_uint(f);
    unsigned int r = (x + 0x7FFFu + ((x >> 16) & 1u)) >> 16;
    return (u16)r;
}

// ---------------------------------------------------------------- fused casts
__global__ __launch_bounds__(256) void cast_all(const float* __restrict__ hs,
                                                const float* __restrict__ Wq,
                                                const float* __restrict__ Wk,
                                                const float* __restrict__ Wv,
                                                const float* __restrict__ Wo,
                                                u16* __restrict__ hsb,
                                                u16* __restrict__ wcat,
                                                u16* __restrict__ wob) {
    int i = blockIdx.x * 256 + threadIdx.x;   // 0 .. 4194303 quads
    const float* src; u16* dst; int off;
    if (i < 1048576)      { src = hs; dst = hsb;            off = i; }
    else if (i < 2097152) { src = Wq; dst = wcat;           off = i - 1048576; }
    else if (i < 2621440) { src = Wk; dst = wcat + 4194304; off = i - 2097152; }
    else if (i < 3145728) { src = Wv; dst = wcat + 6291456; off = i - 2621440; }
    else                  { src = Wo; dst = wob;            off = i - 3145728; }
    f32x4 v = reinterpret_cast<const f32x4*>(src)[off];
    u16x4 o;
    o[0] = f2b(v[0]); o[1] = f2b(v[1]); o[2] = f2b(v[2]); o[3] = f2b(v[3]);
    reinterpret_cast<u16x4*>(dst)[off] = o;
}

// ---------------------------------------------------------------- fused QKV GEMM
// C = hsb[2048][2048] * wcat[4096][2048]^T, 128x128 tiles, 4 waves, WM=4/WN=1:
// each wave owns 32 full rows -> RoPE pair (d,d+64) = (acc[n],acc[n+4]) lane-local,
// row L2-norm = 16-lane shfl tree. Epilogue writes qb/kb (rope+norm+scale, bf16)
// and vt (transposed bf16) directly -- no fp32 qkvf intermediate.
__global__ __launch_bounds__(256) void gemm_qkv(const u16* __restrict__ A,     // hsb
                                                const u16* __restrict__ B,     // wcat
                                                const float* __restrict__ cosb,
                                                const float* __restrict__ sinb,
                                                const float* __restrict__ sqkw,
                                                u16* __restrict__ qb,          // [16][S][128]
                                                u16* __restrict__ kb,          // [8][S][128]
                                                u16* __restrict__ vt) {        // [1024][S]
    const int K = 2048;
    __shared__ alignas(16) u16 As[2][128 * 64];
    __shared__ alignas(16) u16 Bs[2][128 * 64];
    int tid = threadIdx.x, lane = tid & 63, wave = tid >> 6;
    int row0 = blockIdx.y * 128, col0 = blockIdx.x * 128;
    int wr = wave * 32;                       // WM=4, WN=1
    int l15 = lane & 15, lg = lane >> 4;

    f32x4 acc[2][8] = {};

    auto stage = [&](int bf, int k0) {
#pragma unroll
        for (int i = 0; i < 4; i++) {
            int slot = i * 4 + wave;
            int r = slot * 8 + (lane >> 3);
            int c = lane & 7;
            __builtin_amdgcn_global_load_lds(AS1(A + (size_t)(row0 + r) * K + k0 + c * 8),
                                             AS3(&As[bf][slot * 512]), 16, 0, 0);
            __builtin_amdgcn_global_load_lds(AS1(B + (size_t)(col0 + r) * K + k0 + c * 8),
                                             AS3(&Bs[bf][slot * 512]), 16, 0, 0);
        }
    };

    stage(0, 0);
    __syncthreads();

    int nk = K >> 6, buf = 0;
    for (int t = 0; t < nk; ++t) {
        if (t + 1 < nk) stage(buf ^ 1, (t + 1) * 64);

        __builtin_amdgcn_s_setprio(1);
#pragma unroll
        for (int kk = 0; kk < 2; kk++) {
            bf16x8 af[2], bg[8];
#pragma unroll
            for (int m = 0; m < 2; m++)
                af[m] = *reinterpret_cast<const bf16x8*>(&As[buf][(wr + m * 16 + l15) * 64 + kk * 32 + lg * 8]);
#pragma unroll
            for (int n = 0; n < 8; n++)
                bg[n] = *reinterpret_cast<const bf16x8*>(&Bs[buf][(n * 16 + l15) * 64 + kk * 32 + lg * 8]);
#pragma unroll
            for (int m = 0; m < 2; m++)
#pragma unroll
                for (int n = 0; n < 8; n++)
                    acc[m][n] = __builtin_amdgcn_mfma_f32_16x16x32_bf16(af[m], bg[n], acc[m][n], 0, 0, 0);
        }
        __builtin_amdgcn_s_setprio(0);

        __syncthreads();
        buf ^= 1;
    }

    int bx = blockIdx.x;   // 0..15 Q heads, 16..23 K heads, 24..31 V heads
    if (bx < 24) {
        // Q or K: RoPE + L2 norm (+ sqk scale for Q), row-major bf16 store
        bool isQ = bx < 16;
        float w2[8];
        if (isQ) {
#pragma unroll
            for (int j = 0; j < 8; j++) {
                float w = sqkw[bx * 128 + j * 16 + l15] * 50.f;
                w2[j] = w * w * QSCALE_LOG2E;
            }
        }
        u16* outb = isQ ? (qb + (size_t)bx * S_LEN * 128)
                        : (kb + (size_t)(bx - 16) * S_LEN * 128);
#pragma unroll
        for (int m = 0; m < 2; m++)
#pragma unroll
            for (int r = 0; r < 4; r++) {
                int s = row0 + wr + m * 16 + lg * 4 + r;
                const float* crow = cosb + (size_t)s * 128;
                const float* srow = sinb + (size_t)s * 128;
                float y[8];
                float ss = 0.f;
#pragma unroll
                for (int j = 0; j < 4; j++) {
                    float c  = crow[j * 16 + l15];
                    float sn = srow[j * 16 + l15];
                    float x0 = acc[m][j][r], x1 = acc[m][j + 4][r];
                    float a = x0 * c - x1 * sn;
                    float b = x1 * c + x0 * sn;
                    y[j] = a; y[j + 4] = b;
                    ss += a * a + b * b;
                }
                ss += __shfl_xor(ss, 1);
                ss += __shfl_xor(ss, 2);
                ss += __shfl_xor(ss, 4);
                ss += __shfl_xor(ss, 8);
                float inv = 1.f / (sqrtf(ss) + 1e-8f);
                u16* orow = outb + (size_t)s * 128;
                if (isQ) {
#pragma unroll
                    for (int j = 0; j < 8; j++)
                        orow[j * 16 + l15] = f2b(y[j] * inv * w2[j]);
                } else {
#pragma unroll
                    for (int j = 0; j < 8; j++)
                        orow[j * 16 + l15] = f2b(y[j] * inv);
                }
            }
    } else {
        // V: plain bf16 cast, transposed store vt[g*128+d][s] (4 rows packed)
        int g = bx - 24;
#pragma unroll
        for (int n = 0; n < 8; n++) {
            int d = n * 16 + l15;
            u16* vrow = vt + (size_t)(g * 128 + d) * S_LEN;
#pragma unroll
            for (int m = 0; m < 2; m++) {
                u16x4 pk;
#pragma unroll
                for (int r = 0; r < 4; r++) pk[r] = f2b(acc[m][n][r]);
                *reinterpret_cast<u16x4*>(&vrow[row0 + wr + m * 16 + lg * 4]) = pk;
            }
        }
    }
}

// ---------------------------------------------------------------- GEMM (dbuf 2-phase, 4 waves) for O-proj
template<int BM, int BN, int WM, int WN>
__global__ __launch_bounds__(256) void gemm_t(const u16* __restrict__ A,
                                              const u16* __restrict__ B,
                                              float* __restrict__ C,
                                              int M, int N, int K) {
    constexpr int MR = BM / WM / 16;
    constexpr int NR = BN / WN / 16;
    __shared__ alignas(16) u16 As[2][BM * 64];
    __shared__ alignas(16) u16 Bs[2][BN * 64];
    int tid = threadIdx.x, lane = tid & 63, wave = tid >> 6;
    int row0 = blockIdx.y * BM, col0 = blockIdx.x * BN;
    int wr = (wave / WN) * (BM / WM);
    int wc = (wave % WN) * (BN / WN);
    int l15 = lane & 15, lg = lane >> 4;

    f32x4 acc[MR][NR] = {};

    auto stage = [&](int bf, int k0) {
#pragma unroll
        for (int i = 0; i < BM / 32; i++) {
            int slot = i * 4 + wave;
            int r = slot * 8 + (lane >> 3);
            int c = lane & 7;
            __builtin_amdgcn_global_load_lds(AS1(A + (size_t)(row0 + r) * K + k0 + c * 8),
                                             AS3(&As[bf][slot * 512]), 16, 0, 0);
        }
#pragma unroll
        for (int i = 0; i < BN / 32; i++) {
            int slot = i * 4 + wave;
            int r = slot * 8 + (lane >> 3);
            int c = lane & 7;
            __builtin_amdgcn_global_load_lds(AS1(B + (size_t)(col0 + r) * K + k0 + c * 8),
                                             AS3(&Bs[bf][slot * 512]), 16, 0, 0);
        }
    };

    stage(0, 0);
    __syncthreads();

    int nk = K >> 6, buf = 0;
    for (int t = 0; t < nk; ++t) {
        if (t + 1 < nk) stage(buf ^ 1, (t + 1) * 64);

        __builtin_amdgcn_s_setprio(1);
#pragma unroll
        for (int kk = 0; kk < 2; kk++) {
            bf16x8 af[MR], bg[NR];
#pragma unroll
            for (int m = 0; m < MR; m++)
                af[m] = *reinterpret_cast<const bf16x8*>(&As[buf][(wr + m * 16 + l15) * 64 + kk * 32 + lg * 8]);
#pragma unroll
            for (int n = 0; n < NR; n++)
                bg[n] = *reinterpret_cast<const bf16x8*>(&Bs[buf][(wc + n * 16 + l15) * 64 + kk * 32 + lg * 8]);
#pragma unroll
            for (int m = 0; m < MR; m++)
#pragma unroll
                for (int n = 0; n < NR; n++)
                    acc[m][n] = __builtin_amdgcn_mfma_f32_16x16x32_bf16(af[m], bg[n], acc[m][n], 0, 0, 0);
        }
        __builtin_amdgcn_s_setprio(0);

        __syncthreads();
        buf ^= 1;
    }

#pragma unroll
    for (int m = 0; m < MR; m++)
#pragma unroll
        for (int n = 0; n < NR; n++)
#pragma unroll
            for (int r = 0; r < 4; r++) {
                int row = row0 + wr + m * 16 + lg * 4 + r;
                int col = col0 + wc + n * 16 + l15;
                C[(size_t)row * N + col] = acc[m][n][r];
            }
}

// ---------------------------------------------------------------- MFMA flash attention
// 64 q-rows/block, 4 waves x 16 rows. K-tiles of 64. Single LDS buffer
// (41KB -> 3 blocks/CU), T14 async-STAGE split. Softmax in exp2 space with
// fixed max (nGPT bound |s2|<16.5), defer-max cold path as guard.
__global__ __launch_bounds__(256) void attn_mfma(const u16* __restrict__ Qb,  // [16][S][128]
                                                 const u16* __restrict__ Kb,  // [8][S][128]
                                                 const u16* __restrict__ Vt,  // [1024][S]
                                                 u16* __restrict__ Ao) {      // [S][2048]
    __shared__ alignas(16) u16 Ks[64 * 128];
    __shared__ alignas(16) u16 Vs[128 * 64];
    __shared__ alignas(16) u16 Pb[4][16][72];

    int tid = threadIdx.x, lane = tid & 63, wv = tid >> 6;
    int h = blockIdx.x & (NH - 1);
    int z = blockIdx.x >> 4;
    int qi = (z < 16) ? (31 - z) : (z - 16);   // pair big+small per CU
    int qb0 = qi * 64;
    int g = h >> 1;
    int l15 = lane & 15, lg = lane >> 4;

    // Q fragments from global (one-time, L2-resident); pre-scaled by sqrt(D)*log2e
    bf16x8 qf[4];
    {
        const u16* qrow = Qb + ((size_t)h * S_LEN + qb0 + wv * 16 + l15) * 128;
#pragma unroll
        for (int kd = 0; kd < 4; kd++)
            qf[kd] = *reinterpret_cast<const bf16x8*>(qrow + kd * 32 + lg * 8);
    }

    const u16* kbase = Kb + (size_t)g * S_LEN * 128;
    const u16* vbase = Vt + (size_t)g * 128 * S_LEN;

    // reg-staging mapping: whole-row coverage per wave-write => conflict-free
    int rk = wv * 16 + (lane >> 4);   // K row (+4*i), chunk ck (16B) of 256B row
    int ck = lane & 15;
    int rv = wv * 32 + (lane >> 3);   // V row (+8*i), chunk cv (16B) of 128B row
    int cv = lane & 7;

    u16x8 kreg[4], vreg[4];

    float m2[4], lpart[4];
    f32x4 oacc[8];
#pragma unroll
    for (int r = 0; r < 4; r++) { m2[r] = M2INIT; lpart[r] = 0.f; }
#pragma unroll
    for (int dt = 0; dt < 8; dt++) oacc[dt] = (f32x4){0.f, 0.f, 0.f, 0.f};

    int nt = qi + 1;

    // prologue: load tile 0 into regs
#pragma unroll
    for (int i = 0; i < 4; i++) {
        kreg[i] = *reinterpret_cast<const u16x8*>(kbase + (size_t)(rk + 4 * i) * 128 + ck * 8);
        vreg[i] = *reinterpret_cast<const u16x8*>(vbase + (size_t)(rv + 8 * i) * S_LEN + cv * 8);
    }

    for (int t = 0; t < nt; ++t) {
        int k0 = t * 64;
        __syncthreads();   // all waves done reading previous tile
        // write staged regs -> LDS (swizzled)
#pragma unroll
        for (int i = 0; i < 4; i++) {
            int r = rk + 4 * i;
            *reinterpret_cast<u16x8*>((char*)Ks + r * 256 + ((ck * 16) ^ ((r & 7) << 4))) = kreg[i];
            int r2 = rv + 8 * i;
            *reinterpret_cast<u16x8*>((char*)Vs + r2 * 128 + ((cv * 16) ^ ((r2 & 7) << 4))) = vreg[i];
        }
        __syncthreads();   // LDS visible

        // issue next tile's global loads now; they complete under compute
        if (t + 1 < nt) {
            int kn = k0 + 64;
#pragma unroll
            for (int i = 0; i < 4; i++) {
                kreg[i] = *reinterpret_cast<const u16x8*>(kbase + (size_t)(kn + rk + 4 * i) * 128 + ck * 8);
                vreg[i] = *reinterpret_cast<const u16x8*>(vbase + (size_t)(rv + 8 * i) * S_LEN + kn + cv * 8);
            }
        }

        // S2 = (Q*log2e*sqrt(D)) K^T
        f32x4 sacc[4];
#pragma unroll
        for (int kt = 0; kt < 4; kt++) sacc[kt] = (f32x4){0.f, 0.f, 0.f, 0.f};
        __builtin_amdgcn_s_setprio(1);
#pragma unroll
        for (int kt = 0; kt < 4; kt++) {
            int r = kt * 16 + l15;
#pragma unroll
            for (int kd = 0; kd < 4; kd++) {
                int col = kd * 64 + lg * 16;
                bf16x8 kf = *reinterpret_cast<const bf16x8*>((char*)Ks + r * 256 + (col ^ ((r & 7) << 4)));
                sacc[kt] = __builtin_amdgcn_mfma_f32_16x16x32_bf16(qf[kd], kf, sacc[kt], 0, 0, 0);
            }
        }
        __builtin_amdgcn_s_setprio(0);

        // causal mask (diagonal tile only)
        if (t == nt - 1) {
#pragma unroll
            for (int kt = 0; kt < 4; kt++)
#pragma unroll
                for (int r = 0; r < 4; r++) {
                    int key = k0 + kt * 16 + l15;
                    int q = qb0 + wv * 16 + lg * 4 + r;
                    if (key > q) sacc[kt][r] = -1e30f;
                }
        }

        // softmax, exp2 space, fixed max + defer-max guard
        int need = 0;
#pragma unroll
        for (int r = 0; r < 4; r++) {
            float tm = fmaxf(fmaxf(sacc[0][r], sacc[1][r]), fmaxf(sacc[2][r], sacc[3][r]));
            need |= (tm > m2[r] + 11.5f) ? 1 : 0;
        }
        if (__builtin_expect(__any(need), 0)) {
            // cold path: true online-softmax rescale (universal correctness)
#pragma unroll
            for (int r = 0; r < 4; r++) {
                float tm = fmaxf(fmaxf(sacc[0][r], sacc[1][r]), fmaxf(sacc[2][r], sacc[3][r]));
                tm = fmaxf(tm, __shfl_xor(tm, 1));
                tm = fmaxf(tm, __shfl_xor(tm, 2));
                tm = fmaxf(tm, __shfl_xor(tm, 4));
                tm = fmaxf(tm, __shfl_xor(tm, 8));
                float mn = fmaxf(m2[r], tm);
                float sc = EXP2(m2[r] - mn);
                m2[r] = mn;
                lpart[r] *= sc;
#pragma unroll
                for (int dt = 0; dt < 8; dt++) oacc[dt][r] *= sc;
            }
        }
        float pnew[4][4];
#pragma unroll
        for (int r = 0; r < 4; r++) {
            float p0 = EXP2(sacc[0][r] - m2[r]);
            float p1 = EXP2(sacc[1][r] - m2[r]);
            float p2 = EXP2(sacc[2][r] - m2[r]);
            float p3 = EXP2(sacc[3][r] - m2[r]);
            pnew[0][r] = p0; pnew[1][r] = p1; pnew[2][r] = p2; pnew[3][r] = p3;
            lpart[r] += (p0 + p1) + (p2 + p3);
        }

        // P -> wave-private LDS (re-layout for PV A-frags)
#pragma unroll
        for (int kt = 0; kt < 4; kt++)
#pragma unroll
            for (int r = 0; r < 4; r++)
                Pb[wv][lg * 4 + r][kt * 16 + l15] = f2b(pnew[kt][r]);

        // O += P V
        __builtin_amdgcn_s_setprio(1);
#pragma unroll
        for (int ks = 0; ks < 2; ks++) {
            bf16x8 pf = *reinterpret_cast<const bf16x8*>(&Pb[wv][l15][ks * 32 + lg * 8]);
#pragma unroll
            for (int dt = 0; dt < 8; dt++) {
                int r = dt * 16 + l15;
                int col = ks * 64 + lg * 16;
                bf16x8 vf = *reinterpret_cast<const bf16x8*>((char*)Vs + r * 128 + (col ^ ((r & 7) << 4)));
                oacc[dt] = __builtin_amdgcn_mfma_f32_16x16x32_bf16(pf, vf, oacc[dt], 0, 0, 0);
            }
        }
        __builtin_amdgcn_s_setprio(0);
    }

    // epilogue: one-time l reduce across the 16-lane row groups
    float inv[4];
#pragma unroll
    for (int r = 0; r < 4; r++) {
        float ls = lpart[r];
        ls += __shfl_xor(ls, 1);
        ls += __shfl_xor(ls, 2);
        ls += __shfl_xor(ls, 4);
        ls += __shfl_xor(ls, 8);
        inv[r] = 1.f / ls;
    }
#pragma unroll
    for (int dt = 0; dt < 8; dt++)
#pragma unroll
        for (int r = 0; r < 4; r++) {
            int q = qb0 + wv * 16 + lg * 4 + r;
            Ao[(size_t)q * 2048 + h * 128 + dt * 16 + l15] = f2b(oacc[dt][r] * inv[r]);
        }
}

// ---------------------------------------------------------------- launch
extern "C" void kernel_launch(void* const* d_in, const int* in_sizes, int n_in,
                              void* d_out, int out_size, void* d_ws, size_t ws_size,
                              hipStream_t stream) {
    const float* hs   = (const float*)d_in[0];
    const float* cosb = (const float*)d_in[1];
    const float* sinb = (const float*)d_in[2];
    // d_in[3] attention_mask: pure causal, implemented analytically
    const float* Wq   = (const float*)d_in[4];
    const float* Wk   = (const float*)d_in[5];
    const float* Wv   = (const float*)d_in[6];
    const float* Wo   = (const float*)d_in[7];
    const float* sqkw = (const float*)d_in[8];

    char* ws = (char*)d_ws;
    u16*   hsb  = (u16*)(ws);                       //  8.4 MB
    u16*   wcat = (u16*)(ws + 8388608);             // 16.8 MB (Wq;Wk;Wv)
    u16*   wob  = (u16*)(ws + 25165824);            //  8.4 MB
    u16*   qb   = (u16*)(ws + 33554432);            //  8.4 MB  [16][S][128]
    u16*   kb   = (u16*)(ws + 41943040);            //  4.2 MB  [8][S][128]
    u16*   vt   = (u16*)(ws + 46137344);            //  4.2 MB  [1024][S] (V^T)
    u16*   ao   = (u16*)(ws + 50331648);            //  8.4 MB  [S][2048]

    cast_all<<<16384, 256, 0, stream>>>(hs, Wq, Wk, Wv, Wo, hsb, wcat, wob);

    // fused QKV projection + RoPE + L2 norm + sqk scale + V transpose
    gemm_qkv<<<dim3(32, 16), 256, 0, stream>>>(hsb, wcat, cosb, sinb, sqkw, qb, kb, vt);

    attn_mfma<<<512, 256, 0, stream>>>(qb, kb, vt, ao);

    // output projection -> f32 d_out (128x64 tiles, 4 waves, 512 blocks)
    gemm_t<128, 64, 4, 1><<<dim3(32, 16), 256, 0, stream>>>(ao, wob, (float*)d_out, 2048, 2048, 2048);
}

// Round 9
// 156.842 us; speedup vs baseline: 1.1321x; 1.0448x over previous
//
#include <hip/hip_runtime.h>

typedef unsigned short u16;
typedef __attribute__((ext_vector_type(4))) float f32x4;
typedef __attribute__((ext_vector_type(16))) float f32x16;
typedef __attribute__((ext_vector_type(8))) __bf16 bf16x8;
typedef __attribute__((ext_vector_type(8))) u16 u16x8;
typedef __attribute__((ext_vector_type(4))) u16 u16x4;
typedef __attribute__((ext_vector_type(4))) unsigned int u32x4;

#define S_LEN 2048
#define NH 16
#define NKV 8
// sqrt(128) * log2(e) folded into Q; softmax runs in exp2 space
#define QSCALE_LOG2E 16.322118857f
#define M2INIT 16.6f   /* fixed max: |s2| <= 16.33*(1+eps) << f32 exp2 range -> shift-exact */
#define EXP2(x) __builtin_amdgcn_exp2f(x)

// 2-bit XOR swizzles (write and read use the SAME function -> involution)
#define SWZK(r) (((((r) & 7) << 4)) ^ (((((r) >> 3) & 1)) << 7))   /* 256B rows */
#define SWZV(r) (((((r) & 7) << 4)) ^ (((((r) >> 3) & 1)) << 6))   /* 128B rows */

#define AS1(p) ((const __attribute__((address_space(1))) void*)(p))
#define AS3(p) ((__attribute__((address_space(3))) void*)(p))

__device__ __forceinline__ float b2f(u16 u) {
    return __uint_as_float(((unsigned int)u) << 16);
}
__device__ __forceinline__ u16 f2b(float f) {
    unsigned int x = __float_as_uint(f);
    unsigned int r = (x + 0x7FFFu + ((x >> 16) & 1u)) >> 16;
    return (u16)r;
}

// ---------------------------------------------------------------- fused casts
__global__ __launch_bounds__(256) void cast_all(const float* __restrict__ hs,
                                                const float* __restrict__ Wq,
                                                const float* __restrict__ Wk,
                                                const float* __restrict__ Wv,
                                                const float* __restrict__ Wo,
                                                u16* __restrict__ hsb,
                                                u16* __restrict__ wcat,
                                                u16* __restrict__ wob) {
    int i = blockIdx.x * 256 + threadIdx.x;   // 0 .. 4194303 quads
    const float* src; u16* dst; int off;
    if (i < 1048576)      { src = hs; dst = hsb;            off = i; }
    else if (i < 2097152) { src = Wq; dst = wcat;           off = i - 1048576; }
    else if (i < 2621440) { src = Wk; dst = wcat + 4194304; off = i - 2097152; }
    else if (i < 3145728) { src = Wv; dst = wcat + 6291456; off = i - 2621440; }
    else                  { src = Wo; dst = wob;            off = i - 3145728; }
    f32x4 v = reinterpret_cast<const f32x4*>(src)[off];
    u16x4 o;
    o[0] = f2b(v[0]); o[1] = f2b(v[1]); o[2] = f2b(v[2]); o[3] = f2b(v[3]);
    reinterpret_cast<u16x4*>(dst)[off] = o;
}

// ---------------------------------------------------------------- fused QKV GEMM (unchanged, round-8 verified)
__global__ __launch_bounds__(256) void gemm_qkv(const u16* __restrict__ A,     // hsb
                                                const u16* __restrict__ B,     // wcat
                                                const float* __restrict__ cosb,
                                                const float* __restrict__ sinb,
                                                const float* __restrict__ sqkw,
                                                u16* __restrict__ qb,          // [16][S][128]
                                                u16* __restrict__ kb,          // [8][S][128]
                                                u16* __restrict__ vt) {        // [1024][S]
    const int K = 2048;
    __shared__ alignas(16) u16 As[2][128 * 64];
    __shared__ alignas(16) u16 Bs[2][128 * 64];
    int tid = threadIdx.x, lane = tid & 63, wave = tid >> 6;
    int row0 = blockIdx.y * 128, col0 = blockIdx.x * 128;
    int wr = wave * 32;                       // WM=4, WN=1
    int l15 = lane & 15, lg = lane >> 4;

    f32x4 acc[2][8] = {};

    auto stage = [&](int bf, int k0) {
#pragma unroll
        for (int i = 0; i < 4; i++) {
            int slot = i * 4 + wave;
            int r = slot * 8 + (lane >> 3);
            int c = lane & 7;
            __builtin_amdgcn_global_load_lds(AS1(A + (size_t)(row0 + r) * K + k0 + c * 8),
                                             AS3(&As[bf][slot * 512]), 16, 0, 0);
            __builtin_amdgcn_global_load_lds(AS1(B + (size_t)(col0 + r) * K + k0 + c * 8),
                                             AS3(&Bs[bf][slot * 512]), 16, 0, 0);
        }
    };

    stage(0, 0);
    __syncthreads();

    int nk = K >> 6, buf = 0;
    for (int t = 0; t < nk; ++t) {
        if (t + 1 < nk) stage(buf ^ 1, (t + 1) * 64);

        __builtin_amdgcn_s_setprio(1);
#pragma unroll
        for (int kk = 0; kk < 2; kk++) {
            bf16x8 af[2], bg[8];
#pragma unroll
            for (int m = 0; m < 2; m++)
                af[m] = *reinterpret_cast<const bf16x8*>(&As[buf][(wr + m * 16 + l15) * 64 + kk * 32 + lg * 8]);
#pragma unroll
            for (int n = 0; n < 8; n++)
                bg[n] = *reinterpret_cast<const bf16x8*>(&Bs[buf][(n * 16 + l15) * 64 + kk * 32 + lg * 8]);
#pragma unroll
            for (int m = 0; m < 2; m++)
#pragma unroll
                for (int n = 0; n < 8; n++)
                    acc[m][n] = __builtin_amdgcn_mfma_f32_16x16x32_bf16(af[m], bg[n], acc[m][n], 0, 0, 0);
        }
        __builtin_amdgcn_s_setprio(0);

        __syncthreads();
        buf ^= 1;
    }

    int bx = blockIdx.x;   // 0..15 Q heads, 16..23 K heads, 24..31 V heads
    if (bx < 24) {
        bool isQ = bx < 16;
        float w2[8];
        if (isQ) {
#pragma unroll
            for (int j = 0; j < 8; j++) {
                float w = sqkw[bx * 128 + j * 16 + l15] * 50.f;
                w2[j] = w * w * QSCALE_LOG2E;
            }
        }
        u16* outb = isQ ? (qb + (size_t)bx * S_LEN * 128)
                        : (kb + (size_t)(bx - 16) * S_LEN * 128);
#pragma unroll
        for (int m = 0; m < 2; m++)
#pragma unroll
            for (int r = 0; r < 4; r++) {
                int s = row0 + wr + m * 16 + lg * 4 + r;
                const float* crow = cosb + (size_t)s * 128;
                const float* srow = sinb + (size_t)s * 128;
                float y[8];
                float ss = 0.f;
#pragma unroll
                for (int j = 0; j < 4; j++) {
                    float c  = crow[j * 16 + l15];
                    float sn = srow[j * 16 + l15];
                    float x0 = acc[m][j][r], x1 = acc[m][j + 4][r];
                    float a = x0 * c - x1 * sn;
                    float b = x1 * c + x0 * sn;
                    y[j] = a; y[j + 4] = b;
                    ss += a * a + b * b;
                }
                ss += __shfl_xor(ss, 1);
                ss += __shfl_xor(ss, 2);
                ss += __shfl_xor(ss, 4);
                ss += __shfl_xor(ss, 8);
                float inv = 1.f / (sqrtf(ss) + 1e-8f);
                u16* orow = outb + (size_t)s * 128;
                if (isQ) {
#pragma unroll
                    for (int j = 0; j < 8; j++)
                        orow[j * 16 + l15] = f2b(y[j] * inv * w2[j]);
                } else {
#pragma unroll
                    for (int j = 0; j < 8; j++)
                        orow[j * 16 + l15] = f2b(y[j] * inv);
                }
            }
    } else {
        int g = bx - 24;
#pragma unroll
        for (int n = 0; n < 8; n++) {
            int d = n * 16 + l15;
            u16* vrow = vt + (size_t)(g * 128 + d) * S_LEN;
#pragma unroll
            for (int m = 0; m < 2; m++) {
                u16x4 pk;
#pragma unroll
                for (int r = 0; r < 4; r++) pk[r] = f2b(acc[m][n][r]);
                *reinterpret_cast<u16x4*>(&vrow[row0 + wr + m * 16 + lg * 4]) = pk;
            }
        }
    }
}

// ---------------------------------------------------------------- GEMM (dbuf 2-phase) for O-proj
template<int BM, int BN, int WM, int WN>
__global__ __launch_bounds__(256) void gemm_t(const u16* __restrict__ A,
                                              const u16* __restrict__ B,
                                              float* __restrict__ C,
                                              int M, int N, int K) {
    constexpr int MR = BM / WM / 16;
    constexpr int NR = BN / WN / 16;
    __shared__ alignas(16) u16 As[2][BM * 64];
    __shared__ alignas(16) u16 Bs[2][BN * 64];
    int tid = threadIdx.x, lane = tid & 63, wave = tid >> 6;
    int row0 = blockIdx.y * BM, col0 = blockIdx.x * BN;
    int wr = (wave / WN) * (BM / WM);
    int wc = (wave % WN) * (BN / WN);
    int l15 = lane & 15, lg = lane >> 4;

    f32x4 acc[MR][NR] = {};

    auto stage = [&](int bf, int k0) {
#pragma unroll
        for (int i = 0; i < BM / 32; i++) {
            int slot = i * 4 + wave;
            int r = slot * 8 + (lane >> 3);
            int c = lane & 7;
            __builtin_amdgcn_global_load_lds(AS1(A + (size_t)(row0 + r) * K + k0 + c * 8),
                                             AS3(&As[bf][slot * 512]), 16, 0, 0);
        }
#pragma unroll
        for (int i = 0; i < BN / 32; i++) {
            int slot = i * 4 + wave;
            int r = slot * 8 + (lane >> 3);
            int c = lane & 7;
            __builtin_amdgcn_global_load_lds(AS1(B + (size_t)(col0 + r) * K + k0 + c * 8),
                                             AS3(&Bs[bf][slot * 512]), 16, 0, 0);
        }
    };

    stage(0, 0);
    __syncthreads();

    int nk = K >> 6, buf = 0;
    for (int t = 0; t < nk; ++t) {
        if (t + 1 < nk) stage(buf ^ 1, (t + 1) * 64);

        __builtin_amdgcn_s_setprio(1);
#pragma unroll
        for (int kk = 0; kk < 2; kk++) {
            bf16x8 af[MR], bg[NR];
#pragma unroll
            for (int m = 0; m < MR; m++)
                af[m] = *reinterpret_cast<const bf16x8*>(&As[buf][(wr + m * 16 + l15) * 64 + kk * 32 + lg * 8]);
#pragma unroll
            for (int n = 0; n < NR; n++)
                bg[n] = *reinterpret_cast<const bf16x8*>(&Bs[buf][(wc + n * 16 + l15) * 64 + kk * 32 + lg * 8]);
#pragma unroll
            for (int m = 0; m < MR; m++)
#pragma unroll
                for (int n = 0; n < NR; n++)
                    acc[m][n] = __builtin_amdgcn_mfma_f32_16x16x32_bf16(af[m], bg[n], acc[m][n], 0, 0, 0);
        }
        __builtin_amdgcn_s_setprio(0);

        __syncthreads();
        buf ^= 1;
    }

#pragma unroll
    for (int m = 0; m < MR; m++)
#pragma unroll
        for (int n = 0; n < NR; n++)
#pragma unroll
            for (int r = 0; r < 4; r++) {
                int row = row0 + wr + m * 16 + lg * 4 + r;
                int col = col0 + wc + n * 16 + l15;
                C[(size_t)row * N + col] = acc[m][n][r];
            }
}

// ---------------------------------------------------------------- MFMA flash attention (32x32, swapped operands)
// 64 q-rows/block, 4 waves: wave = (rowgrp wv>>1)*32 rows x (keyhalf wv&1)*32 keys.
// S^T = mfma_32x32x16(K, Q): lane holds one q (lane&31), 16 keys in regs ->
// fixed-max exp2 softmax is fully lane-local (no shuffles, no LDS).
// P -> PV B-frags via in-register pack + shfl_xor(32). O^T partials per wave,
// merged across key-halves once in epilogue (LDS scratch overlaid on Ks/Vs).
__global__ __launch_bounds__(256) void attn_mfma(const u16* __restrict__ Qb,  // [16][S][128]
                                                 const u16* __restrict__ Kb,  // [8][S][128]
                                                 const u16* __restrict__ Vt,  // [1024][S]
                                                 u16* __restrict__ Ao) {      // [S][2048]
    __shared__ alignas(16) char smem[50432];
    u16* Ks = (u16*)smem;                      // [64][256B] 16KB (loop)
    u16* Vs = (u16*)(smem + 16384);            // [128][128B] 16KB (loop)
    float* scrO = (float*)smem;                // [2][128][32] f32 32KB (epilogue)
    float* scrL = (float*)(smem + 32768);      // [2][32] f32 (epilogue)
    u16*   scrT = (u16*)(smem + 33024);        // [64][136] u16 (epilogue)

    int tid = threadIdx.x, lane = tid & 63, wv = tid >> 6;
    int h = blockIdx.x & (NH - 1);
    int z = blockIdx.x >> 4;
    int qi = (z < 16) ? (31 - z) : (z - 16);   // pair big+small per CU
    int qb0 = qi * 64;
    int g = h >> 1;
    int l31 = lane & 31, hi = lane >> 5;
    int qoff = (wv >> 1) * 32, koff = (wv & 1) * 32;
    int qabs = qb0 + qoff + l31;

    // Q fragments (B-operand layout: col=q=lane&31, k = hi*8+j), pre-scaled
    bf16x8 qf[8];
    {
        const u16* qrow = Qb + ((size_t)h * S_LEN + qabs) * 128;
#pragma unroll
        for (int kd = 0; kd < 8; kd++)
            qf[kd] = *reinterpret_cast<const bf16x8*>(qrow + kd * 16 + hi * 8);
    }

    const u16* kbase = Kb + (size_t)g * S_LEN * 128;
    const u16* vbase = Vt + (size_t)g * 128 * S_LEN;

    // T14 reg-staging mapping (whole-row coverage per wave => conflict-free writes)
    int rk = wv * 16 + (lane >> 4);   // K row (+4*i), chunk ck of 256B row
    int ck = lane & 15;
    int rv = wv * 32 + (lane >> 3);   // V row (+8*i), chunk cv of 128B row
    int cv = lane & 7;

    u16x8 kreg[4], vreg[4];
    f32x16 oacc[4] = {};
    float lpart = 0.f;

    int nt = qi + 1;

    // prologue: tile 0 into regs
#pragma unroll
    for (int i = 0; i < 4; i++) {
        kreg[i] = *reinterpret_cast<const u16x8*>(kbase + (size_t)(rk + 4 * i) * 128 + ck * 8);
        vreg[i] = *reinterpret_cast<const u16x8*>(vbase + (size_t)(rv + 8 * i) * S_LEN + cv * 8);
    }

    for (int t = 0; t < nt; ++t) {
        int k0 = t * 64;
        __syncthreads();   // all waves done reading previous tile
#pragma unroll
        for (int i = 0; i < 4; i++) {
            int r = rk + 4 * i;
            *reinterpret_cast<u16x8*>((char*)Ks + r * 256 + ((ck * 16) ^ SWZK(r))) = kreg[i];
            int r2 = rv + 8 * i;
            *reinterpret_cast<u16x8*>((char*)Vs + r2 * 128 + ((cv * 16) ^ SWZV(r2))) = vreg[i];
        }
        __syncthreads();   // LDS visible

        if (t + 1 < nt) {  // prefetch next tile under compute
            int kn = k0 + 64;
#pragma unroll
            for (int i = 0; i < 4; i++) {
                kreg[i] = *reinterpret_cast<const u16x8*>(kbase + (size_t)(kn + rk + 4 * i) * 128 + ck * 8);
                vreg[i] = *reinterpret_cast<const u16x8*>(vbase + (size_t)(rv + 8 * i) * S_LEN + kn + cv * 8);
            }
        }

        // S^T = K . Q  (two interleaved acc chains over kd)
        f32x16 s0 = {}, s1 = {};
        int krow = koff + l31;
        char* krp = (char*)Ks + krow * 256;
        int ksw = SWZK(krow);
        __builtin_amdgcn_s_setprio(1);
#pragma unroll
        for (int kd = 0; kd < 8; kd += 2) {
            bf16x8 kf0 = *reinterpret_cast<const bf16x8*>(krp + ((kd * 32 + hi * 16) ^ ksw));
            bf16x8 kf1 = *reinterpret_cast<const bf16x8*>(krp + (((kd + 1) * 32 + hi * 16) ^ ksw));
            s0 = __builtin_amdgcn_mfma_f32_32x32x16_bf16(kf0, qf[kd], s0, 0, 0, 0);
            s1 = __builtin_amdgcn_mfma_f32_32x32x16_bf16(kf1, qf[kd + 1], s1, 0, 0, 0);
        }
        __builtin_amdgcn_s_setprio(0);

        // softmax (exp2 space, fixed max; lane-local; causal mask on diagonal tile)
        float p[16];
        bool maskt = (t == nt - 1);
#pragma unroll
        for (int r = 0; r < 16; r++) {
            float s = s0[r] + s1[r];
            if (maskt) {
                int key = k0 + koff + (r & 3) + 8 * (r >> 2) + 4 * hi;
                if (key > qabs) s = -1e30f;
            }
            float pv = EXP2(s - M2INIT);
            p[r] = pv;
            lpart += pv;
        }

        // P -> bf16 B-fragments (in-register transpose via shfl_xor 32)
        bf16x8 pf[2];
#pragma unroll
        for (int ks = 0; ks < 2; ks++) {
            int b = ks * 8;
            unsigned int A0 = (unsigned int)f2b(p[b + 0]) | ((unsigned int)f2b(p[b + 1]) << 16);
            unsigned int A1 = (unsigned int)f2b(p[b + 2]) | ((unsigned int)f2b(p[b + 3]) << 16);
            unsigned int A2 = (unsigned int)f2b(p[b + 4]) | ((unsigned int)f2b(p[b + 5]) << 16);
            unsigned int A3 = (unsigned int)f2b(p[b + 6]) | ((unsigned int)f2b(p[b + 7]) << 16);
            unsigned int S0 = __shfl_xor(A0, 32);
            unsigned int S1 = __shfl_xor(A1, 32);
            unsigned int S2 = __shfl_xor(A2, 32);
            unsigned int S3 = __shfl_xor(A3, 32);
            u32x4 w;
            w[0] = hi ? S2 : A0;
            w[1] = hi ? S3 : A1;
            w[2] = hi ? A2 : S0;
            w[3] = hi ? A3 : S1;
            pf[ks] = *reinterpret_cast<bf16x8*>(&w);
        }

        // O^T += V^T . P   (4 independent db chains)
        __builtin_amdgcn_s_setprio(1);
#pragma unroll
        for (int db = 0; db < 4; db++) {
            int vr = db * 32 + l31;
            char* vrp = (char*)Vs + vr * 128;
            int vsw = SWZV(vr);
#pragma unroll
            for (int ks = 0; ks < 2; ks++) {
                bf16x8 vf = *reinterpret_cast<const bf16x8*>(vrp + ((koff * 2 + ks * 32 + hi * 16) ^ vsw));
                oacc[db] = __builtin_amdgcn_mfma_f32_32x32x16_bf16(vf, pf[ks], oacc[db], 0, 0, 0);
            }
        }
        __builtin_amdgcn_s_setprio(0);
    }

    // ---- epilogue: merge key-halves, normalize, coalesced store
    float lw = lpart + __shfl_xor(lpart, 32);   // this wave's 32-key row sum, q=l31
    int rg = wv >> 1;
    __syncthreads();   // all tile LDS reads done before scratch overlay
    if (wv & 1) {      // key-half 1 waves publish partials
#pragma unroll
        for (int db = 0; db < 4; db++)
#pragma unroll
            for (int r = 0; r < 16; r++) {
                int d = db * 32 + (r & 3) + 8 * (r >> 2) + 4 * hi;
                scrO[(rg * 128 + d) * 32 + l31] = oacc[db][r];
            }
        if (lane < 32) scrL[rg * 32 + l31] = lw;
    }
    __syncthreads();
    if (!(wv & 1)) {   // key-half 0 waves merge + normalize -> bf16 scratch
        float inv = 1.f / (lw + scrL[rg * 32 + l31]);
#pragma unroll
        for (int db = 0; db < 4; db++)
#pragma unroll
            for (int r = 0; r < 16; r++) {
                int d = db * 32 + (r & 3) + 8 * (r >> 2) + 4 * hi;
                float o = (oacc[db][r] + scrO[(rg * 128 + d) * 32 + l31]) * inv;
                scrT[(rg * 32 + l31) * 136 + d] = f2b(o);
            }
    }
    __syncthreads();
    // cooperative coalesced store
    for (int i = tid; i < 64 * 16; i += 256) {
        int q = i >> 4, c = i & 15;
        u16x8 v = *reinterpret_cast<const u16x8*>(&scrT[q * 136 + c * 8]);
        *reinterpret_cast<u16x8*>(&Ao[(size_t)(qb0 + q) * 2048 + h * 128 + c * 8]) = v;
    }
}

// ---------------------------------------------------------------- launch
extern "C" void kernel_launch(void* const* d_in, const int* in_sizes, int n_in,
                              void* d_out, int out_size, void* d_ws, size_t ws_size,
                              hipStream_t stream) {
    const float* hs   = (const float*)d_in[0];
    const float* cosb = (const float*)d_in[1];
    const float* sinb = (const float*)d_in[2];
    // d_in[3] attention_mask: pure causal, implemented analytically
    const float* Wq   = (const float*)d_in[4];
    const float* Wk   = (const float*)d_in[5];
    const float* Wv   = (const float*)d_in[6];
    const float* Wo   = (const float*)d_in[7];
    const float* sqkw = (const float*)d_in[8];

    char* ws = (char*)d_ws;
    u16*   hsb  = (u16*)(ws);                       //  8.4 MB
    u16*   wcat = (u16*)(ws + 8388608);             // 16.8 MB (Wq;Wk;Wv)
    u16*   wob  = (u16*)(ws + 25165824);            //  8.4 MB
    u16*   qb   = (u16*)(ws + 33554432);            //  8.4 MB  [16][S][128]
    u16*   kb   = (u16*)(ws + 41943040);            //  4.2 MB  [8][S][128]
    u16*   vt   = (u16*)(ws + 46137344);            //  4.2 MB  [1024][S] (V^T)
    u16*   ao   = (u16*)(ws + 50331648);            //  8.4 MB  [S][2048]

    cast_all<<<16384, 256, 0, stream>>>(hs, Wq, Wk, Wv, Wo, hsb, wcat, wob);

    // fused QKV projection + RoPE + L2 norm + sqk scale + V transpose
    gemm_qkv<<<dim3(32, 16), 256, 0, stream>>>(hsb, wcat, cosb, sinb, sqkw, qb, kb, vt);

    attn_mfma<<<512, 256, 0, stream>>>(qb, kb, vt, ao);

    // output projection -> f32 d_out (128x64 tiles, 4 waves, 512 blocks)
    gemm_t<128, 64, 4, 1><<<dim3(32, 16), 256, 0, stream>>>(ao, wob, (float*)d_out, 2048, 2048, 2048);
}

// Round 10
// 148.730 us; speedup vs baseline: 1.1938x; 1.0545x over previous
//
#include <hip/hip_runtime.h>

typedef unsigned short u16;
typedef __attribute__((ext_vector_type(4))) float f32x4;
typedef __attribute__((ext_vector_type(16))) float f32x16;
typedef __attribute__((ext_vector_type(8))) __bf16 bf16x8;
typedef __attribute__((ext_vector_type(8))) u16 u16x8;
typedef __attribute__((ext_vector_type(4))) u16 u16x4;
typedef __attribute__((ext_vector_type(4))) unsigned int u32x4;

#define S_LEN 2048
#define NH 16
#define NKV 8
// sqrt(128) * log2(e) folded into Q; softmax runs in exp2 space
#define QSCALE_LOG2E 16.322118857f
#define M2INIT 16.6f   /* fixed max: |s2| <= 16.33*(1+eps) -> shift-exact */
#define EXP2(x) __builtin_amdgcn_exp2f(x)

// attn swizzles (round-9, verified)
#define SWZK(r) (((((r) & 7) << 4)) ^ (((((r) >> 3) & 1)) << 7))   /* 256B rows */
#define SWZV(r) (((((r) & 7) << 4)) ^ (((((r) >> 3) & 1)) << 6))   /* 128B rows */

#define AS1(p) ((const __attribute__((address_space(1))) void*)(p))
#define AS3(p) ((__attribute__((address_space(3))) void*)(p))

// counted-vmcnt + raw barrier, one asm block so nothing interleaves.
// memory clobber: no memory op (gload_lds/ds_read) may cross.
#define PIPE_WAIT6() asm volatile("s_waitcnt vmcnt(6)\ns_barrier" ::: "memory")
#define PIPE_WAIT4() asm volatile("s_waitcnt vmcnt(4)\ns_barrier" ::: "memory")
#define PIPE_WAIT0() asm volatile("s_waitcnt vmcnt(0)\ns_barrier" ::: "memory")

__device__ __forceinline__ float b2f(u16 u) {
    return __uint_as_float(((unsigned int)u) << 16);
}
__device__ __forceinline__ u16 f2b(float f) {
    unsigned int x = __float_as_uint(f);
    unsigned int r = (x + 0x7FFFu + ((x >> 16) & 1u)) >> 16;
    return (u16)r;
}

// ---------------------------------------------------------------- fused casts
__global__ __launch_bounds__(256) void cast_all(const float* __restrict__ hs,
                                                const float* __restrict__ Wq,
                                                const float* __restrict__ Wk,
                                                const float* __restrict__ Wv,
                                                const float* __restrict__ Wo,
                                                u16* __restrict__ hsb,
                                                u16* __restrict__ wcat,
                                                u16* __restrict__ wob) {
    int i = blockIdx.x * 256 + threadIdx.x;   // 0 .. 4194303 quads
    const float* src; u16* dst; int off;
    if (i < 1048576)      { src = hs; dst = hsb;            off = i; }
    else if (i < 2097152) { src = Wq; dst = wcat;           off = i - 1048576; }
    else if (i < 2621440) { src = Wk; dst = wcat + 4194304; off = i - 2097152; }
    else if (i < 3145728) { src = Wv; dst = wcat + 6291456; off = i - 2621440; }
    else                  { src = Wo; dst = wob;            off = i - 3145728; }
    f32x4 v = reinterpret_cast<const f32x4*>(src)[off];
    u16x4 o;
    o[0] = f2b(v[0]); o[1] = f2b(v[1]); o[2] = f2b(v[2]); o[3] = f2b(v[3]);
    reinterpret_cast<u16x4*>(dst)[off] = o;
}

// ---------------------------------------------------------------- fused QKV GEMM (3-buf counted-vmcnt pipeline)
// C = hsb[2048][2048] * wcat[4096][2048]^T. BM=128 x BN=256, BK=64, 8 waves,
// wave = 32 rows x 128 cols (one full head of the 2-head column block) ->
// RoPE pair (d,d+64) = (acc[n],acc[n+4]) lane-local. 3 LDS buffers (144KB,
// 1 block/CU), stage(t+2) issued each iter; per-tile sync = one asm
// "s_waitcnt vmcnt(6); s_barrier" (loads cross barriers, never drained).
// LDS XOR-swizzled: inverse-swizzled gload source + swizzled ds_read (T2).
__global__ __launch_bounds__(512) void gemm_qkv(const u16* __restrict__ A,     // hsb
                                                const u16* __restrict__ B,     // wcat
                                                const float* __restrict__ cosb,
                                                const float* __restrict__ sinb,
                                                const float* __restrict__ sqkw,
                                                u16* __restrict__ qb,          // [16][S][128]
                                                u16* __restrict__ kb,          // [8][S][128]
                                                u16* __restrict__ vt) {        // [1024][S]
    const int K = 2048;
    __shared__ alignas(16) u16 As[3][128 * 64];   //  48 KB
    __shared__ alignas(16) u16 Bs[3][256 * 64];   //  96 KB
    int tid = threadIdx.x, lane = tid & 63, wave = tid >> 6;   // 8 waves
    int row0 = blockIdx.y * 128, col0 = blockIdx.x * 256;
    int wr = (wave >> 1) * 32;        // 4 M row-groups
    int wc = (wave & 1) * 128;        // 2 N head-columns
    int l15 = lane & 15, lg = lane >> 4;

    f32x4 acc[2][8] = {};

    // stage: linear LDS dest, inverse-swizzled per-lane global source.
    // 6 gload_lds per wave per tile (A:2, B:4).
    auto stage = [&](int bf, int k0) {
#pragma unroll
        for (int i = 0; i < 2; i++) {
            int slot = i * 8 + wave;                 // 0..15 (wave-uniform)
            int r = slot * 8 + (lane >> 3);          // A row 0..127
            int c = (lane & 7) ^ (r & 7);            // source 16B chunk
            __builtin_amdgcn_global_load_lds(AS1(A + (size_t)(row0 + r) * K + k0 + c * 8),
                                             AS3(&As[bf][slot * 512]), 16, 0, 0);
        }
#pragma unroll
        for (int i = 0; i < 4; i++) {
            int slot = i * 8 + wave;                 // 0..31
            int r = slot * 8 + (lane >> 3);          // B row 0..255
            int c = (lane & 7) ^ (r & 7);
            __builtin_amdgcn_global_load_lds(AS1(B + (size_t)(col0 + r) * K + k0 + c * 8),
                                             AS3(&Bs[bf][slot * 512]), 16, 0, 0);
        }
    };

    const int nk = K >> 6;            // 32
    stage(0, 0);
    stage(1, 64);

    for (int t = 0; t < nk; ++t) {
        int buf = t % 3;
        __builtin_amdgcn_sched_barrier(0);   // keep prior MFMAs + lgkm waits above
        if (t + 1 < nk) PIPE_WAIT6(); else PIPE_WAIT0();
        if (t + 2 < nk) stage((t + 2) % 3, (t + 2) * 64);

        __builtin_amdgcn_s_setprio(1);
#pragma unroll
        for (int kk = 0; kk < 2; kk++) {
            bf16x8 af[2], bg[8];
#pragma unroll
            for (int m = 0; m < 2; m++) {
                int r = wr + m * 16 + l15;
                af[m] = *reinterpret_cast<const bf16x8*>(&As[buf][r * 64 + (((kk * 4 + lg) ^ (r & 7)) * 8)]);
            }
#pragma unroll
            for (int n = 0; n < 8; n++) {
                int r = wc + n * 16 + l15;
                bg[n] = *reinterpret_cast<const bf16x8*>(&Bs[buf][r * 64 + (((kk * 4 + lg) ^ (r & 7)) * 8)]);
            }
#pragma unroll
            for (int m = 0; m < 2; m++)
#pragma unroll
                for (int n = 0; n < 8; n++)
                    acc[m][n] = __builtin_amdgcn_mfma_f32_16x16x32_bf16(af[m], bg[n], acc[m][n], 0, 0, 0);
        }
        __builtin_amdgcn_s_setprio(0);
    }

    // epilogue (round-8 verified logic; head column = c32, per-wave uniform)
    int c32 = blockIdx.x * 2 + (wave & 1);   // 0..15 Q, 16..23 K, 24..31 V
    if (c32 < 24) {
        bool isQ = c32 < 16;
        float w2[8];
        if (isQ) {
#pragma unroll
            for (int j = 0; j < 8; j++) {
                float w = sqkw[c32 * 128 + j * 16 + l15] * 50.f;
                w2[j] = w * w * QSCALE_LOG2E;
            }
        }
        u16* outb = isQ ? (qb + (size_t)c32 * S_LEN * 128)
                        : (kb + (size_t)(c32 - 16) * S_LEN * 128);
#pragma unroll
        for (int m = 0; m < 2; m++)
#pragma unroll
            for (int r = 0; r < 4; r++) {
                int s = row0 + wr + m * 16 + lg * 4 + r;
                const float* crow = cosb + (size_t)s * 128;
                const float* srow = sinb + (size_t)s * 128;
                float y[8];
                float ss = 0.f;
#pragma unroll
                for (int j = 0; j < 4; j++) {
                    float c  = crow[j * 16 + l15];
                    float sn = srow[j * 16 + l15];
                    float x0 = acc[m][j][r], x1 = acc[m][j + 4][r];
                    float a = x0 * c - x1 * sn;
                    float b = x1 * c + x0 * sn;
                    y[j] = a; y[j + 4] = b;
                    ss += a * a + b * b;
                }
                ss += __shfl_xor(ss, 1);
                ss += __shfl_xor(ss, 2);
                ss += __shfl_xor(ss, 4);
                ss += __shfl_xor(ss, 8);
                float inv = 1.f / (sqrtf(ss) + 1e-8f);
                u16* orow = outb + (size_t)s * 128;
                if (isQ) {
#pragma unroll
                    for (int j = 0; j < 8; j++)
                        orow[j * 16 + l15] = f2b(y[j] * inv * w2[j]);
                } else {
#pragma unroll
                    for (int j = 0; j < 8; j++)
                        orow[j * 16 + l15] = f2b(y[j] * inv);
                }
            }
    } else {
        int g = c32 - 24;
#pragma unroll
        for (int n = 0; n < 8; n++) {
            int d = n * 16 + l15;
            u16* vrow = vt + (size_t)(g * 128 + d) * S_LEN;
#pragma unroll
            for (int m = 0; m < 2; m++) {
                u16x4 pk;
#pragma unroll
                for (int r = 0; r < 4; r++) pk[r] = f2b(acc[m][n][r]);
                *reinterpret_cast<u16x4*>(&vrow[row0 + wr + m * 16 + lg * 4]) = pk;
            }
        }
    }
}

// ---------------------------------------------------------------- O-proj GEMM (same 3-buf pipeline, 128x128, 8 waves)
__global__ __launch_bounds__(512) void gemm_o(const u16* __restrict__ A,
                                              const u16* __restrict__ B,
                                              float* __restrict__ C,
                                              int M, int N, int K) {
    __shared__ alignas(16) u16 As[3][128 * 64];   // 48 KB
    __shared__ alignas(16) u16 Bs[3][128 * 64];   // 48 KB
    int tid = threadIdx.x, lane = tid & 63, wave = tid >> 6;
    int row0 = blockIdx.y * 128, col0 = blockIdx.x * 128;
    int wr = (wave >> 1) * 32;        // 4 M groups
    int wc = (wave & 1) * 64;         // 2 N groups
    int l15 = lane & 15, lg = lane >> 4;

    f32x4 acc[2][4] = {};

    auto stage = [&](int bf, int k0) {
#pragma unroll
        for (int i = 0; i < 2; i++) {
            int slot = i * 8 + wave;
            int r = slot * 8 + (lane >> 3);
            int c = (lane & 7) ^ (r & 7);
            __builtin_amdgcn_global_load_lds(AS1(A + (size_t)(row0 + r) * K + k0 + c * 8),
                                             AS3(&As[bf][slot * 512]), 16, 0, 0);
        }
#pragma unroll
        for (int i = 0; i < 2; i++) {
            int slot = i * 8 + wave;
            int r = slot * 8 + (lane >> 3);
            int c = (lane & 7) ^ (r & 7);
            __builtin_amdgcn_global_load_lds(AS1(B + (size_t)(col0 + r) * K + k0 + c * 8),
                                             AS3(&Bs[bf][slot * 512]), 16, 0, 0);
        }
    };

    const int nk = K >> 6;
    stage(0, 0);
    stage(1, 64);

    for (int t = 0; t < nk; ++t) {
        int buf = t % 3;
        __builtin_amdgcn_sched_barrier(0);
        if (t + 1 < nk) PIPE_WAIT4(); else PIPE_WAIT0();
        if (t + 2 < nk) stage((t + 2) % 3, (t + 2) * 64);

        __builtin_amdgcn_s_setprio(1);
#pragma unroll
        for (int kk = 0; kk < 2; kk++) {
            bf16x8 af[2], bg[4];
#pragma unroll
            for (int m = 0; m < 2; m++) {
                int r = wr + m * 16 + l15;
                af[m] = *reinterpret_cast<const bf16x8*>(&As[buf][r * 64 + (((kk * 4 + lg) ^ (r & 7)) * 8)]);
            }
#pragma unroll
            for (int n = 0; n < 4; n++) {
                int r = wc + n * 16 + l15;
                bg[n] = *reinterpret_cast<const bf16x8*>(&Bs[buf][r * 64 + (((kk * 4 + lg) ^ (r & 7)) * 8)]);
            }
#pragma unroll
            for (int m = 0; m < 2; m++)
#pragma unroll
                for (int n = 0; n < 4; n++)
                    acc[m][n] = __builtin_amdgcn_mfma_f32_16x16x32_bf16(af[m], bg[n], acc[m][n], 0, 0, 0);
        }
        __builtin_amdgcn_s_setprio(0);
    }

#pragma unroll
    for (int m = 0; m < 2; m++)
#pragma unroll
        for (int n = 0; n < 4; n++)
#pragma unroll
            for (int r = 0; r < 4; r++) {
                int row = row0 + wr + m * 16 + lg * 4 + r;
                int col = col0 + wc + n * 16 + l15;
                C[(size_t)row * N + col] = acc[m][n][r];
            }
}

// ---------------------------------------------------------------- MFMA flash attention (round-9, unchanged)
__global__ __launch_bounds__(256) void attn_mfma(const u16* __restrict__ Qb,  // [16][S][128]
                                                 const u16* __restrict__ Kb,  // [8][S][128]
                                                 const u16* __restrict__ Vt,  // [1024][S]
                                                 u16* __restrict__ Ao) {      // [S][2048]
    __shared__ alignas(16) char smem[50432];
    u16* Ks = (u16*)smem;                      // [64][256B] 16KB (loop)
    u16* Vs = (u16*)(smem + 16384);            // [128][128B] 16KB (loop)
    float* scrO = (float*)smem;                // [2][128][32] f32 32KB (epilogue)
    float* scrL = (float*)(smem + 32768);      // [2][32] f32 (epilogue)
    u16*   scrT = (u16*)(smem + 33024);        // [64][136] u16 (epilogue)

    int tid = threadIdx.x, lane = tid & 63, wv = tid >> 6;
    int h = blockIdx.x & (NH - 1);
    int z = blockIdx.x >> 4;
    int qi = (z < 16) ? (31 - z) : (z - 16);   // pair big+small per CU
    int qb0 = qi * 64;
    int g = h >> 1;
    int l31 = lane & 31, hi = lane >> 5;
    int qoff = (wv >> 1) * 32, koff = (wv & 1) * 32;
    int qabs = qb0 + qoff + l31;

    bf16x8 qf[8];
    {
        const u16* qrow = Qb + ((size_t)h * S_LEN + qabs) * 128;
#pragma unroll
        for (int kd = 0; kd < 8; kd++)
            qf[kd] = *reinterpret_cast<const bf16x8*>(qrow + kd * 16 + hi * 8);
    }

    const u16* kbase = Kb + (size_t)g * S_LEN * 128;
    const u16* vbase = Vt + (size_t)g * 128 * S_LEN;

    int rk = wv * 16 + (lane >> 4);
    int ck = lane & 15;
    int rv = wv * 32 + (lane >> 3);
    int cv = lane & 7;

    u16x8 kreg[4], vreg[4];
    f32x16 oacc[4] = {};
    float lpart = 0.f;

    int nt = qi + 1;

#pragma unroll
    for (int i = 0; i < 4; i++) {
        kreg[i] = *reinterpret_cast<const u16x8*>(kbase + (size_t)(rk + 4 * i) * 128 + ck * 8);
        vreg[i] = *reinterpret_cast<const u16x8*>(vbase + (size_t)(rv + 8 * i) * S_LEN + cv * 8);
    }

    for (int t = 0; t < nt; ++t) {
        int k0 = t * 64;
        __syncthreads();
#pragma unroll
        for (int i = 0; i < 4; i++) {
            int r = rk + 4 * i;
            *reinterpret_cast<u16x8*>((char*)Ks + r * 256 + ((ck * 16) ^ SWZK(r))) = kreg[i];
            int r2 = rv + 8 * i;
            *reinterpret_cast<u16x8*>((char*)Vs + r2 * 128 + ((cv * 16) ^ SWZV(r2))) = vreg[i];
        }
        __syncthreads();

        if (t + 1 < nt) {
            int kn = k0 + 64;
#pragma unroll
            for (int i = 0; i < 4; i++) {
                kreg[i] = *reinterpret_cast<const u16x8*>(kbase + (size_t)(kn + rk + 4 * i) * 128 + ck * 8);
                vreg[i] = *reinterpret_cast<const u16x8*>(vbase + (size_t)(rv + 8 * i) * S_LEN + kn + cv * 8);
            }
        }

        f32x16 s0 = {}, s1 = {};
        int krow = koff + l31;
        char* krp = (char*)Ks + krow * 256;
        int ksw = SWZK(krow);
        __builtin_amdgcn_s_setprio(1);
#pragma unroll
        for (int kd = 0; kd < 8; kd += 2) {
            bf16x8 kf0 = *reinterpret_cast<const bf16x8*>(krp + ((kd * 32 + hi * 16) ^ ksw));
            bf16x8 kf1 = *reinterpret_cast<const bf16x8*>(krp + (((kd + 1) * 32 + hi * 16) ^ ksw));
            s0 = __builtin_amdgcn_mfma_f32_32x32x16_bf16(kf0, qf[kd], s0, 0, 0, 0);
            s1 = __builtin_amdgcn_mfma_f32_32x32x16_bf16(kf1, qf[kd + 1], s1, 0, 0, 0);
        }
        __builtin_amdgcn_s_setprio(0);

        float p[16];
        bool maskt = (t == nt - 1);
#pragma unroll
        for (int r = 0; r < 16; r++) {
            float s = s0[r] + s1[r];
            if (maskt) {
                int key = k0 + koff + (r & 3) + 8 * (r >> 2) + 4 * hi;
                if (key > qabs) s = -1e30f;
            }
            float pv = EXP2(s - M2INIT);
            p[r] = pv;
            lpart += pv;
        }

        bf16x8 pf[2];
#pragma unroll
        for (int ks = 0; ks < 2; ks++) {
            int b = ks * 8;
            unsigned int A0 = (unsigned int)f2b(p[b + 0]) | ((unsigned int)f2b(p[b + 1]) << 16);
            unsigned int A1 = (unsigned int)f2b(p[b + 2]) | ((unsigned int)f2b(p[b + 3]) << 16);
            unsigned int A2 = (unsigned int)f2b(p[b + 4]) | ((unsigned int)f2b(p[b + 5]) << 16);
            unsigned int A3 = (unsigned int)f2b(p[b + 6]) | ((unsigned int)f2b(p[b + 7]) << 16);
            unsigned int S0 = __shfl_xor(A0, 32);
            unsigned int S1 = __shfl_xor(A1, 32);
            unsigned int S2 = __shfl_xor(A2, 32);
            unsigned int S3 = __shfl_xor(A3, 32);
            u32x4 w;
            w[0] = hi ? S2 : A0;
            w[1] = hi ? S3 : A1;
            w[2] = hi ? A2 : S0;
            w[3] = hi ? A3 : S1;
            pf[ks] = *reinterpret_cast<bf16x8*>(&w);
        }

        __builtin_amdgcn_s_setprio(1);
#pragma unroll
        for (int db = 0; db < 4; db++) {
            int vr = db * 32 + l31;
            char* vrp = (char*)Vs + vr * 128;
            int vsw = SWZV(vr);
#pragma unroll
            for (int ks = 0; ks < 2; ks++) {
                bf16x8 vf = *reinterpret_cast<const bf16x8*>(vrp + ((koff * 2 + ks * 32 + hi * 16) ^ vsw));
                oacc[db] = __builtin_amdgcn_mfma_f32_32x32x16_bf16(vf, pf[ks], oacc[db], 0, 0, 0);
            }
        }
        __builtin_amdgcn_s_setprio(0);
    }

    float lw = lpart + __shfl_xor(lpart, 32);
    int rg = wv >> 1;
    __syncthreads();
    if (wv & 1) {
#pragma unroll
        for (int db = 0; db < 4; db++)
#pragma unroll
            for (int r = 0; r < 16; r++) {
                int d = db * 32 + (r & 3) + 8 * (r >> 2) + 4 * hi;
                scrO[(rg * 128 + d) * 32 + l31] = oacc[db][r];
            }
        if (lane < 32) scrL[rg * 32 + l31] = lw;
    }
    __syncthreads();
    if (!(wv & 1)) {
        float inv = 1.f / (lw + scrL[rg * 32 + l31]);
#pragma unroll
        for (int db = 0; db < 4; db++)
#pragma unroll
            for (int r = 0; r < 16; r++) {
                int d = db * 32 + (r & 3) + 8 * (r >> 2) + 4 * hi;
                float o = (oacc[db][r] + scrO[(rg * 128 + d) * 32 + l31]) * inv;
                scrT[(rg * 32 + l31) * 136 + d] = f2b(o);
            }
    }
    __syncthreads();
    for (int i = tid; i < 64 * 16; i += 256) {
        int q = i >> 4, c = i & 15;
        u16x8 v = *reinterpret_cast<const u16x8*>(&scrT[q * 136 + c * 8]);
        *reinterpret_cast<u16x8*>(&Ao[(size_t)(qb0 + q) * 2048 + h * 128 + c * 8]) = v;
    }
}

// ---------------------------------------------------------------- launch
extern "C" void kernel_launch(void* const* d_in, const int* in_sizes, int n_in,
                              void* d_out, int out_size, void* d_ws, size_t ws_size,
                              hipStream_t stream) {
    const float* hs   = (const float*)d_in[0];
    const float* cosb = (const float*)d_in[1];
    const float* sinb = (const float*)d_in[2];
    // d_in[3] attention_mask: pure causal, implemented analytically
    const float* Wq   = (const float*)d_in[4];
    const float* Wk   = (const float*)d_in[5];
    const float* Wv   = (const float*)d_in[6];
    const float* Wo   = (const float*)d_in[7];
    const float* sqkw = (const float*)d_in[8];

    char* ws = (char*)d_ws;
    u16*   hsb  = (u16*)(ws);                       //  8.4 MB
    u16*   wcat = (u16*)(ws + 8388608);             // 16.8 MB (Wq;Wk;Wv)
    u16*   wob  = (u16*)(ws + 25165824);            //  8.4 MB
    u16*   qb   = (u16*)(ws + 33554432);            //  8.4 MB  [16][S][128]
    u16*   kb   = (u16*)(ws + 41943040);            //  4.2 MB  [8][S][128]
    u16*   vt   = (u16*)(ws + 46137344);            //  4.2 MB  [1024][S] (V^T)
    u16*   ao   = (u16*)(ws + 50331648);            //  8.4 MB  [S][2048]

    cast_all<<<16384, 256, 0, stream>>>(hs, Wq, Wk, Wv, Wo, hsb, wcat, wob);

    // fused QKV projection + RoPE + L2 norm + sqk scale + V transpose
    // 128x256 tiles, 8 waves, 256 blocks = 1/CU exact
    gemm_qkv<<<dim3(16, 16), 512, 0, stream>>>(hsb, wcat, cosb, sinb, sqkw, qb, kb, vt);

    attn_mfma<<<512, 256, 0, stream>>>(qb, kb, vt, ao);

    // output projection -> f32 d_out (128x128 tiles, 8 waves, 256 blocks)
    gemm_o<<<dim3(16, 16), 512, 0, stream>>>(ao, wob, (float*)d_out, 2048, 2048, 2048);
}